// Round 2
// baseline (219.418 us; speedup 1.0000x reference)
//
#include <hip/hip_runtime.h>

#define BOND   64
#define SITES  256
#define HALF   128
#define NBATCH 128
#define OUTD   10

// d_ws float layout:
//   P0 : [0 .. 1048576)        left-packed  [128 steps][32 g][64 j] float4
//   P1 : [1048576 .. 2097152)  right-packed (transposed, step k = site 255-k)
//   vecs: [2097152 .. 2113536) [2][128][64] propagated end vectors
#define P1_OFF   1048576
#define VEC_OFF  2097152
#define SITE_F4  2048          // float4s per packed site (64*64*2 floats)
#define LPITCH   132           // LDS transpose pitch (floats), 16B-aligned rows

// ---------------------------------------------------------------------------
// Pack kernel: one block per site, LDS transpose so BOTH global reads and
// writes are fully coalesced.  (unchanged)
//   side0 step s:        P0[s][g][j]     = {c0[2g][j], c1[2g][j], c0[2g+1][j], c1[2g+1][j]}
//   side1 step 255-s:    P1[255-s][g][j] = {c0[j][2g], c1[j][2g], c0[j][2g+1], c1[j][2g+1]}
// ---------------------------------------------------------------------------
__global__ void __launch_bounds__(256)
mps_pack_kernel(const float* __restrict__ cores, float* __restrict__ P) {
  __shared__ __align__(16) float ld[64 * LPITCH];
  const int s = (int)blockIdx.x;
  const int t = (int)threadIdx.x;
  const float4* src = (const float4*)(cores + (size_t)s * 8192);
  #pragma unroll
  for (int k = 0; k < 8; ++k) {
    const int m = t + 256 * k;              // float4 index in [0,2048)
    const int row = m >> 5;                 // l
    const int c4  = m & 31;                 // float4 within row
    *(float4*)&ld[row * LPITCH + c4 * 4] = src[m];
  }
  __syncthreads();
  const bool right = s >= HALF;
  const int step = right ? (SITES - 1 - s) : s;
  float4* out = (float4*)(P + (right ? P1_OFF : 0)) + (size_t)step * SITE_F4;
  #pragma unroll
  for (int k = 0; k < 8; ++k) {
    const int m = t + 256 * k;              // out float4 index = g*64 + j
    const int g = m >> 6;
    const int j = m & 63;
    float4 v;
    if (!right) {
      const float2 a  = *(const float2*)&ld[(2 * g) * LPITCH + 2 * j];
      const float2 b2 = *(const float2*)&ld[(2 * g + 1) * LPITCH + 2 * j];
      v = make_float4(a.x, a.y, b2.x, b2.y);
    } else {
      v = *(const float4*)&ld[j * LPITCH + 4 * g];
    }
    out[m] = v;
  }
}

// ---------------------------------------------------------------------------
// Chain kernel, barrier-free: 64 blocks x 256 threads (4 waves).
// Wave = one full (batch, side) chain over the whole l-range. Lane j owns
// v[j]; v-broadcast is a wave-local LDS write + 16 broadcast ds_read_b128
// (same address across lanes = conflict-free). NO __syncthreads anywhere ->
// the 32-float4 matrix prefetch for step i+1 stays in flight with no drain.
// 4 waves of a block run the SAME side (same matrix addresses) -> L1 reuse.
// side = blockIdx&1 pins each side's 4MB packed stream to its XCD's L2.
// __launch_bounds__(256,1): 1 wave/SIMD by design, VGPR budget 512 so the
// A[32]/B[32] float4 double-buffer is real this time.
// ---------------------------------------------------------------------------
__global__ void __launch_bounds__(256, 1)
mps_chain_kernel(const float* __restrict__ input,   // [128][256][2]
                 const float* __restrict__ P,       // packed cores (in ws)
                 const float* __restrict__ lvec,
                 const float* __restrict__ rvec,
                 float* __restrict__ vout) {        // ws + VEC_OFF
  __shared__ __align__(16) float vbuf[4][BOND];     // per-wave v
  __shared__ __align__(16) float xbuf[4][HALF][2];  // per-wave x, step order

  const int t    = (int)threadIdx.x;
  const int w    = t >> 6;
  const int lane = t & 63;
  const int side = (int)blockIdx.x & 1;
  const int b    = ((int)blockIdx.x >> 1) * 4 + w;  // wave's batch

  float* xw = &xbuf[w][0][0];
  // stage this wave's x half, pre-reversed for side 1 (one-time cost).
  {
    const float4 g =
        ((const float4*)(input + (size_t)b * SITES * 2 + side * HALF * 2))[lane];
    if (!side) {
      ((float4*)xw)[lane] = g;                       // steps 2*lane, 2*lane+1
    } else {
      // f4 covers sites 128+2*lane (g.x,g.y) and 128+2*lane+1 (g.z,g.w)
      // step = 255 - site
      ((float2*)xw)[HALF - 1 - 2 * lane] = make_float2(g.x, g.y);
      ((float2*)xw)[HALF - 2 - 2 * lane] = make_float2(g.z, g.w);
    }
  }

  float r = side ? rvec[lane] : lvec[lane];          // v[lane], identity-accum
  vbuf[w][lane] = r;

  // lane j's float4 at (step, g): {c0[2g][j], c1[2g][j], c0[2g+1][j], c1[2g+1][j]}
  const float4* base = (const float4*)(P + (side ? P1_OFF : 0)) + lane;

  float4 A[32], B[32];
  #pragma unroll
  for (int j = 0; j < 32; ++j) A[j] = base[j * 64];  // step 0

  #define STEP(CUR, NXT, I)                                                  \
  {                                                                          \
    /* v broadcast first: critical path */                                   \
    float4 vv[16];                                                           \
    _Pragma("unroll")                                                        \
    for (int k = 0; k < 16; ++k) vv[k] = ((const float4*)vbuf[w])[k];        \
    const float2 xv = *(const float2*)&xw[2 * (I)];                          \
    /* prefetch next step's matrix; clobber pins the issues here */          \
    const int inx = ((I) + 1 < HALF) ? (I) + 1 : (I);                        \
    _Pragma("unroll")                                                        \
    for (int j = 0; j < 32; ++j)                                             \
      NXT[j] = base[(size_t)inx * SITE_F4 + j * 64];                         \
    asm volatile("" ::: "memory");                                           \
    float p0a = 0.f, p1a = 0.f, p0b = 0.f, p1b = 0.f;                        \
    _Pragma("unroll")                                                        \
    for (int q = 0; q < 16; ++q) {                                           \
      const float4 vq = vv[q];          /* v[4q .. 4q+3] */                  \
      const float4 m0 = CUR[2 * q];     /* l = 4q, 4q+1  */                  \
      const float4 m1 = CUR[2 * q + 1]; /* l = 4q+2,4q+3 */                  \
      p0a = __builtin_fmaf(vq.x, m0.x, p0a);                                 \
      p1a = __builtin_fmaf(vq.x, m0.y, p1a);                                 \
      p0b = __builtin_fmaf(vq.z, m1.x, p0b);                                 \
      p1b = __builtin_fmaf(vq.z, m1.y, p1b);                                 \
      p0a = __builtin_fmaf(vq.y, m0.z, p0a);                                 \
      p1a = __builtin_fmaf(vq.y, m0.w, p1a);                                 \
      p0b = __builtin_fmaf(vq.w, m1.z, p0b);                                 \
      p1b = __builtin_fmaf(vq.w, m1.w, p1b);                                 \
    }                                                                        \
    r = __builtin_fmaf(xv.x, p0a + p0b, __builtin_fmaf(xv.y, p1a + p1b, r)); \
    vbuf[w][lane] = r;                                                       \
  }

  for (int i = 0; i < HALF; i += 2) {
    STEP(A, B, i);
    STEP(B, A, i + 1);
  }
  #undef STEP

  vout[((size_t)side * NBATCH + b) * BOND + lane] = r;
}

// ---------------------------------------------------------------------------
// logits[b][o] = sum_{m,r} vL[b][m] * oc[o][m][r] * vR[b][r]
// ---------------------------------------------------------------------------
__global__ void __launch_bounds__(64)
mps_combine_kernel(const float* __restrict__ oc,    // [10][64][64]
                   const float* __restrict__ vecs,  // ws + VEC_OFF
                   float* __restrict__ out) {       // [128][10]
  __shared__ float vl[BOND];
  const int lane = (int)threadIdx.x;
  const int b = (int)blockIdx.x;
  vl[lane] = vecs[b * BOND + lane];
  const float myvr = vecs[NBATCH * BOND + b * BOND + lane];
  float res[OUTD];
  #pragma unroll
  for (int o = 0; o < OUTD; ++o) {
    float acc = 0.f;
    #pragma unroll
    for (int m = 0; m < BOND; ++m)
      acc = __builtin_fmaf(vl[m], oc[((o * BOND) + m) * BOND + lane], acc);
    acc *= myvr;
    #pragma unroll
    for (int off = 32; off > 0; off >>= 1)
      acc += __shfl_xor(acc, off, 64);
    res[o] = acc;
  }
  if (lane == 0) {
    #pragma unroll
    for (int o = 0; o < OUTD; ++o) out[b * OUTD + o] = res[o];
  }
}

extern "C" void kernel_launch(void* const* d_in, const int* in_sizes, int n_in,
                              void* d_out, int out_size, void* d_ws, size_t ws_size,
                              hipStream_t stream) {
  const float* input = (const float*)d_in[0];   // [128][256][2]
  const float* cores = (const float*)d_in[1];   // [256][64][64][2]
  const float* oc    = (const float*)d_in[2];   // [10][64][64]
  const float* lvec  = (const float*)d_in[3];   // [64]
  const float* rvec  = (const float*)d_in[4];   // [64]
  float* ws  = (float*)d_ws;
  float* out = (float*)d_out;                   // [128][10]

  hipLaunchKernelGGL(mps_pack_kernel, dim3(SITES), dim3(256), 0, stream,
                     cores, ws);
  hipLaunchKernelGGL(mps_chain_kernel, dim3(64), dim3(256), 0, stream,
                     input, ws, lvec, rvec, ws + VEC_OFF);
  hipLaunchKernelGGL(mps_combine_kernel, dim3(NBATCH), dim3(64), 0, stream,
                     oc, ws + VEC_OFF, out);
}

// Round 3
// 162.316 us; speedup vs baseline: 1.3518x; 1.3518x over previous
//
#include <hip/hip_runtime.h>

#define BOND   64
#define SITES  256
#define HALF   128
#define NBATCH 128
#define OUTD   10

// d_ws float layout:
//   P0 : [0 .. 1048576)        left-packed  [128 steps][32 g][64 j] float4
//   P1 : [1048576 .. 2097152)  right-packed (transposed, step k = site 255-k)
//   vecs: [2097152 .. 2113536) [2][128][64] propagated end vectors
#define P1_OFF   1048576
#define VEC_OFF  2097152
#define SITE_F4  2048          // float4s per packed site (64*64*2 floats)
#define LPITCH   132           // LDS transpose pitch (floats), 16B-aligned rows

// ---------------------------------------------------------------------------
// Pack kernel: one block per site, LDS transpose so BOTH global reads and
// writes are fully coalesced.  (unchanged)
//   side0 step s:        P0[s][g][j]     = {c0[2g][j], c1[2g][j], c0[2g+1][j], c1[2g+1][j]}
//   side1 step 255-s:    P1[255-s][g][j] = {c0[j][2g], c1[j][2g], c0[j][2g+1], c1[j][2g+1]}
// ---------------------------------------------------------------------------
__global__ void __launch_bounds__(256)
mps_pack_kernel(const float* __restrict__ cores, float* __restrict__ P) {
  __shared__ __align__(16) float ld[64 * LPITCH];
  const int s = (int)blockIdx.x;
  const int t = (int)threadIdx.x;
  const float4* src = (const float4*)(cores + (size_t)s * 8192);
  #pragma unroll
  for (int k = 0; k < 8; ++k) {
    const int m = t + 256 * k;              // float4 index in [0,2048)
    const int row = m >> 5;                 // l
    const int c4  = m & 31;                 // float4 within row
    *(float4*)&ld[row * LPITCH + c4 * 4] = src[m];
  }
  __syncthreads();
  const bool right = s >= HALF;
  const int step = right ? (SITES - 1 - s) : s;
  float4* out = (float4*)(P + (right ? P1_OFF : 0)) + (size_t)step * SITE_F4;
  #pragma unroll
  for (int k = 0; k < 8; ++k) {
    const int m = t + 256 * k;              // out float4 index = g*64 + j
    const int g = m >> 6;
    const int j = m & 63;
    float4 v;
    if (!right) {
      const float2 a  = *(const float2*)&ld[(2 * g) * LPITCH + 2 * j];
      const float2 b2 = *(const float2*)&ld[(2 * g + 1) * LPITCH + 2 * j];
      v = make_float4(a.x, a.y, b2.x, b2.y);
    } else {
      v = *(const float4*)&ld[j * LPITCH + 4 * g];
    }
    out[m] = v;
  }
}

// ---------------------------------------------------------------------------
// Chain kernel: 256 blocks x 64 threads. ONE WAVE = ONE FULL (batch, side)
// CHAIN. All 256 CUs busy, per-CU matrix traffic = the minimum 32 KB/step
// (R2's 4-waves-per-CU duplicated it 4x -> L1 thrash; that was the 155us).
// No barriers at all. The v-broadcast is a wave-local ds_write + 16
// broadcast ds_read_b128 (same address on all lanes = conflict-free,
// DS ops are in-order within a wave).
// sched_barrier(0) between the 32 prefetch issues and the FMA wall stops
// the compiler from sinking the loads back to their uses (which is what
// silently killed the double buffer in R2: VGPR_Count=152 proved A/B were
// collapsed). With the fence, step i+1's loads fly during step i's FMAs.
// __launch_bounds__(64,1): 512-VGPR budget for A[32]+B[32]+vv[16] ~ 350.
// ---------------------------------------------------------------------------
__global__ void __launch_bounds__(64, 1)
mps_chain_kernel(const float* __restrict__ input,   // [128][256][2]
                 const float* __restrict__ P,       // packed cores (in ws)
                 const float* __restrict__ lvec,
                 const float* __restrict__ rvec,
                 float* __restrict__ vout) {        // ws + VEC_OFF
  __shared__ __align__(16) float vbuf[BOND];        // running v, own-lane slot
  __shared__ __align__(16) float xsh[HALF][2];      // x in step order

  const int lane = (int)threadIdx.x;                // 0..63
  const int side = (int)blockIdx.x & 1;             // per-XCD side pinning
  const int b    = (int)blockIdx.x >> 1;            // batch 0..127

  // stage x half, pre-reversed for side 1 (one-time; wave-local DS in-order)
  {
    const float4 g =
        ((const float4*)(input + (size_t)b * SITES * 2 + side * HALF * 2))[lane];
    if (!side) {
      ((float4*)xsh)[lane] = g;                     // steps 2*lane, 2*lane+1
    } else {
      // float4 covers sites 128+2*lane (g.x,g.y) and 128+2*lane+1 (g.z,g.w)
      // step = 255 - site
      ((float2*)xsh)[HALF - 1 - 2 * lane] = make_float2(g.x, g.y);
      ((float2*)xsh)[HALF - 2 - 2 * lane] = make_float2(g.z, g.w);
    }
  }

  float r = side ? rvec[lane] : lvec[lane];         // v[lane]; identity-accum

  // lane j's float4 at (step, g): {c0[2g][j], c1[2g][j], c0[2g+1][j], c1[2g+1][j]}
  const float4* base = (const float4*)(P + (side ? P1_OFF : 0)) + lane;

  float4 A[32], B[32];
  #pragma unroll
  for (int j = 0; j < 32; ++j) A[j] = base[j * 64]; // step 0

  #define STEP(CUR, NXT, I)                                                  \
  {                                                                          \
    vbuf[lane] = r;                                                          \
    float4 vv[16];                                                           \
    _Pragma("unroll")                                                        \
    for (int k = 0; k < 16; ++k) vv[k] = ((const float4*)vbuf)[k];           \
    const float2 xv = *(const float2*)xsh[(I)];                              \
    const int inx = ((I) + 1 < HALF) ? (I) + 1 : (I);                        \
    _Pragma("unroll")                                                        \
    for (int j = 0; j < 32; ++j)                                             \
      NXT[j] = base[(size_t)inx * SITE_F4 + j * 64];                         \
    __builtin_amdgcn_sched_barrier(0); /* pin load ISSUES above the FMAs */  \
    float p0a = 0.f, p1a = 0.f, p0b = 0.f, p1b = 0.f;                        \
    _Pragma("unroll")                                                        \
    for (int q = 0; q < 16; ++q) {                                           \
      const float4 vq = vv[q];          /* v[4q .. 4q+3] */                  \
      const float4 m0 = CUR[2 * q];     /* l = 4q, 4q+1  */                  \
      const float4 m1 = CUR[2 * q + 1]; /* l = 4q+2,4q+3 */                  \
      p0a = __builtin_fmaf(vq.x, m0.x, p0a);                                 \
      p1a = __builtin_fmaf(vq.x, m0.y, p1a);                                 \
      p0b = __builtin_fmaf(vq.z, m1.x, p0b);                                 \
      p1b = __builtin_fmaf(vq.z, m1.y, p1b);                                 \
      p0a = __builtin_fmaf(vq.y, m0.z, p0a);                                 \
      p1a = __builtin_fmaf(vq.y, m0.w, p1a);                                 \
      p0b = __builtin_fmaf(vq.w, m1.z, p0b);                                 \
      p1b = __builtin_fmaf(vq.w, m1.w, p1b);                                 \
    }                                                                        \
    r = __builtin_fmaf(xv.x, p0a + p0b, __builtin_fmaf(xv.y, p1a + p1b, r)); \
  }

  for (int i = 0; i < HALF; i += 2) {
    STEP(A, B, i);
    STEP(B, A, i + 1);
  }
  #undef STEP

  vout[((size_t)side * NBATCH + b) * BOND + lane] = r;
}

// ---------------------------------------------------------------------------
// logits[b][o] = sum_{m,r} vL[b][m] * oc[o][m][r] * vR[b][r]
// ---------------------------------------------------------------------------
__global__ void __launch_bounds__(64)
mps_combine_kernel(const float* __restrict__ oc,    // [10][64][64]
                   const float* __restrict__ vecs,  // ws + VEC_OFF
                   float* __restrict__ out) {       // [128][10]
  __shared__ float vl[BOND];
  const int lane = (int)threadIdx.x;
  const int b = (int)blockIdx.x;
  vl[lane] = vecs[b * BOND + lane];
  const float myvr = vecs[NBATCH * BOND + b * BOND + lane];
  float res[OUTD];
  #pragma unroll
  for (int o = 0; o < OUTD; ++o) {
    float acc = 0.f;
    #pragma unroll
    for (int m = 0; m < BOND; ++m)
      acc = __builtin_fmaf(vl[m], oc[((o * BOND) + m) * BOND + lane], acc);
    acc *= myvr;
    #pragma unroll
    for (int off = 32; off > 0; off >>= 1)
      acc += __shfl_xor(acc, off, 64);
    res[o] = acc;
  }
  if (lane == 0) {
    #pragma unroll
    for (int o = 0; o < OUTD; ++o) out[b * OUTD + o] = res[o];
  }
}

extern "C" void kernel_launch(void* const* d_in, const int* in_sizes, int n_in,
                              void* d_out, int out_size, void* d_ws, size_t ws_size,
                              hipStream_t stream) {
  const float* input = (const float*)d_in[0];   // [128][256][2]
  const float* cores = (const float*)d_in[1];   // [256][64][64][2]
  const float* oc    = (const float*)d_in[2];   // [10][64][64]
  const float* lvec  = (const float*)d_in[3];   // [64]
  const float* rvec  = (const float*)d_in[4];   // [64]
  float* ws  = (float*)d_ws;
  float* out = (float*)d_out;                   // [128][10]

  hipLaunchKernelGGL(mps_pack_kernel, dim3(SITES), dim3(256), 0, stream,
                     cores, ws);
  hipLaunchKernelGGL(mps_chain_kernel, dim3(256), dim3(64), 0, stream,
                     input, ws, lvec, rvec, ws + VEC_OFF);
  hipLaunchKernelGGL(mps_combine_kernel, dim3(NBATCH), dim3(64), 0, stream,
                     oc, ws + VEC_OFF, out);
}